// Round 6
// baseline (91.060 us; speedup 1.0000x reference)
//
#include <hip/hip_runtime.h>
#include <math.h>

#define NB 8
#define TT 2048
#define DD 1024
#define NTI 16            // 2048 / 128 t-tiles
#define NPAIR 136         // NTI*(NTI+1)/2

typedef __attribute__((ext_vector_type(8))) short short8;
typedef __attribute__((ext_vector_type(4))) float floatx4;

__device__ inline unsigned short f2bf(float f) {
    unsigned u = __builtin_bit_cast(unsigned, f);
    unsigned r = (u + 0x7fffu + ((u >> 16) & 1u)) >> 16;
    return (unsigned short)r;
}

__device__ inline float bf2f(unsigned short u) {
    return __builtin_bit_cast(float, (unsigned)u << 16);
}

__device__ inline float fast_gelu(float x) {
    // tanh(z) = 1 - 2/(exp(2z)+1); __expf -> v_exp_f32
    float z = 0.7978845608028654f * (x + 0.044715f * x * x * x);
    float e = __expf(2.0f * z);
    float th = 1.0f - 2.0f / (e + 1.0f);
    return 0.5f * x * (1.0f + th);
}

// ------- kernel A: gelu + row norm + ema dot, wave-per-row -------------------
__global__ __launch_bounds__(256) void k_gelu_norm(
        const float* __restrict__ x, const float* __restrict__ ema,
        unsigned short* __restrict__ onrm, float* __restrict__ norms,
        float* __restrict__ ema_sim) {
    int row = blockIdx.x * 4 + (threadIdx.x >> 6);
    int lane = threadIdx.x & 63;
    const float4* xr = reinterpret_cast<const float4*>(x + (size_t)row * DD);
    const float4* er = reinterpret_cast<const float4*>(ema);
    float g[16];
    float ss = 0.f, dt = 0.f, e2 = 0.f;
#pragma unroll
    for (int j = 0; j < 4; ++j) {
        float4 v = xr[j * 64 + lane];
        float4 e = er[j * 64 + lane];
        float vv[4] = {v.x, v.y, v.z, v.w};
        float ee[4] = {e.x, e.y, e.z, e.w};
        e2 += ee[0] * ee[0] + ee[1] * ee[1] + ee[2] * ee[2] + ee[3] * ee[3];
#pragma unroll
        for (int i = 0; i < 4; ++i) {
            float o = fast_gelu(vv[i]);
            g[j * 4 + i] = o;
            ss += o * o;
            dt += o * ee[i];
        }
    }
#pragma unroll
    for (int m = 1; m < 64; m <<= 1) {
        ss += __shfl_xor(ss, m);
        dt += __shfl_xor(dt, m);
        e2 += __shfl_xor(e2, m);
    }
    float nrm = fmaxf(sqrtf(ss), 1e-12f);
    float inv = 1.0f / nrm;
    float einv = 1.0f / fmaxf(sqrtf(e2), 1e-12f);
    ushort4* orow = reinterpret_cast<ushort4*>(onrm + (size_t)row * DD);
#pragma unroll
    for (int j = 0; j < 4; ++j) {
        ushort4 u;
        u.x = f2bf(g[j * 4 + 0] * inv);
        u.y = f2bf(g[j * 4 + 1] * inv);
        u.z = f2bf(g[j * 4 + 2] * inv);
        u.w = f2bf(g[j * 4 + 3] * inv);
        orow[j * 64 + lane] = u;
    }
    if (lane == 0) {
        norms[row] = nrm;
        ema_sim[row] = dt * inv * einv;
    }
}

// -------- kernel B: causal max similarity, 128x128 tiled bf16 MFMA GEMM ------
// grid = NB*136 lower-tri 128x128 tile pairs, XCD-swizzled (batch per XCD,
// onrm slice L2-resident). 4 waves, each 64x64 (4x4 frags), BK=64.
// T4 counted-vmcnt double-buffer schedule: issue stage(kt+1), wait only own
// stage(kt) 8 loads (vmcnt(8)), raw s_barrier (=> ALL waves' stage(kt)
// complete), compute, barrier. No vmcnt(0) drain in the main loop.
__global__ void k_seqmax(const unsigned short* __restrict__ onrm,
                         float* __restrict__ part) {
    __shared__ unsigned short lds[2][2][8192];   // [buf][A/B][128 x 64 bf16] 64 KB

    int id = blockIdx.x;
    int nid = (id & 7) * NPAIR + (id >> 3);      // bijective: 1088 % 8 == 0
    int b = nid / NPAIR;
    int p = nid % NPAIR;
    int ti = (int)((sqrtf(8.0f * (float)p + 1.0f) - 1.0f) * 0.5f);
    while ((ti + 1) * (ti + 2) / 2 <= p) ++ti;
    while (ti * (ti + 1) / 2 > p) --ti;
    int sj = p - ti * (ti + 1) / 2;

    int lane = threadIdx.x & 63;
    int wave = threadIdx.x >> 6;
    int wr = wave >> 1, wc = wave & 1;

    const unsigned short* Abase = onrm + (size_t)(b * TT + ti * 128) * DD;
    const unsigned short* Bbase = onrm + (size_t)(b * TT + sj * 128) * DD;

    floatx4 acc[4][4];
#pragma unroll
    for (int i = 0; i < 4; i++)
#pragma unroll
        for (int j = 0; j < 4; j++) acc[i][j] = (floatx4){0.f, 0.f, 0.f, 0.f};

    // stage 128x64 bf16 tile pair into lds[buf]: 16 chunks of 1 KB, 4/wave,
    // 8 global_load_lds (w=16) per wave per stage.
    auto stage = [&](int buf, int kt) {
#pragma unroll
        for (int i = 0; i < 4; ++i) {
            int c = wave * 4 + i;            // chunk 0..15
            int off = c * 1024 + lane * 16;  // linear LDS byte offset
            int row = off >> 7;              // 128 B per row
            int colb = (off & 127) ^ ((row & 7) << 4);
            const char* srcA = (const char*)(Abase + (size_t)row * DD + kt * 64) + colb;
            const char* srcB = (const char*)(Bbase + (size_t)row * DD + kt * 64) + colb;
            __builtin_amdgcn_global_load_lds(
                (const __attribute__((address_space(1))) unsigned int*)srcA,
                (__attribute__((address_space(3))) unsigned int*)((char*)&lds[buf][0][0] + c * 1024),
                16, 0, 0);
            __builtin_amdgcn_global_load_lds(
                (const __attribute__((address_space(1))) unsigned int*)srcB,
                (__attribute__((address_space(3))) unsigned int*)((char*)&lds[buf][1][0] + c * 1024),
                16, 0, 0);
        }
    };

    stage(0, 0);

#pragma unroll
    for (int kt = 0; kt < 16; ++kt) {
        int buf = kt & 1;
        if (kt + 1 < 16) {
            stage(buf ^ 1, kt + 1);
            // own stage(kt) complete (8 oldest); the 8 just issued may fly on
            asm volatile("s_waitcnt vmcnt(8)" ::: "memory");
        } else {
            asm volatile("s_waitcnt vmcnt(0)" ::: "memory");
        }
        __builtin_amdgcn_s_barrier();            // all waves' stage(kt) done
        __builtin_amdgcn_sched_barrier(0);
        const char* Ab = (const char*)&lds[buf][0][0];
        const char* Bb = (const char*)&lds[buf][1][0];
        __builtin_amdgcn_s_setprio(1);
#pragma unroll
        for (int ks = 0; ks < 2; ++ks) {
            short8 af[4], bg[4];
            int cb = ks * 64 + ((lane >> 4) << 4);
#pragma unroll
            for (int f = 0; f < 4; ++f) {
                int ar = wr * 64 + f * 16 + (lane & 15);
                int br = wc * 64 + f * 16 + (lane & 15);
                af[f] = *(const short8*)(Ab + ar * 128 + (cb ^ ((ar & 7) << 4)));
                bg[f] = *(const short8*)(Bb + br * 128 + (cb ^ ((br & 7) << 4)));
            }
#pragma unroll
            for (int fi = 0; fi < 4; ++fi)
#pragma unroll
                for (int fj = 0; fj < 4; ++fj)
                    acc[fi][fj] = __builtin_amdgcn_mfma_f32_16x16x32_bf16(
                        af[fi], bg[fj], acc[fi][fj], 0, 0, 0);
        }
        __builtin_amdgcn_s_setprio(0);
        __builtin_amdgcn_sched_barrier(0);
        __builtin_amdgcn_s_barrier();            // reads of buf done -> restage ok
    }

    // epilogue: strict-causal mask, row-max over this wave's 64-col half,
    // write partial to part[b][sj*2+wc][t]
    int g = lane >> 4;
    int t0g = ti * 128 + wr * 64;
    int s0g = sj * 128 + wc * 64;
#pragma unroll
    for (int fi = 0; fi < 4; ++fi) {
#pragma unroll
        for (int r = 0; r < 4; ++r) {
            int trow = t0g + fi * 16 + g * 4 + r;
            float m = -2.0f;
#pragma unroll
            for (int fj = 0; fj < 4; ++fj) {
                int scol = s0g + fj * 16 + (lane & 15);
                m = fmaxf(m, (scol < trow) ? acc[fi][fj][r] : -2.0f);
            }
#pragma unroll
            for (int msk = 1; msk < 16; msk <<= 1) m = fmaxf(m, __shfl_xor(m, msk));
            if ((lane & 15) == 0)
                part[(((size_t)b * 32 + sj * 2 + wc) << 11) + trow] = m;
        }
    }
}

// ------- kernel C: reduce partials + gate + reconstruct out, wave-per-row ----
__global__ __launch_bounds__(256) void k_gate(
        const unsigned short* __restrict__ onrm, const float* __restrict__ norms,
        float* __restrict__ out, const float* __restrict__ ema_sim,
        const float* __restrict__ part,
        const float* __restrict__ log_tau,
        const float* __restrict__ log_blend,
        const float* __restrict__ logit_blend_seq) {
    int row = blockIdx.x * 4 + (threadIdx.x >> 6);
    int lane = threadIdx.x & 63;
    int b = row >> 11;
    int t = row & (TT - 1);

    int n = 2 * ((t >> 7) + 1);              // 2..32 column-halves present
    float m = (lane < n) ? part[(((size_t)b * 32 + lane) << 11) + t] : -2.0f;
#pragma unroll
    for (int msk = 1; msk < 64; msk <<= 1) m = fmaxf(m, __shfl_xor(m, msk));

    float tau = __expf(log_tau[0]);
    float alpha = 1.f / (1.f + __expf(-log_blend[0]));
    float wseq = 1.f / (1.f + __expf(-logit_blend_seq[0]));
    float es = ema_sim[row];
    float sq = (t > 0) ? m : es;
    float fam = wseq * sq + (1.f - wseq) * es;
    float gate = 1.f - alpha + alpha * __expf(-tau * fam);
    float scale = gate * norms[row];

    const ushort4* ir = reinterpret_cast<const ushort4*>(onrm + (size_t)row * DD);
    float4* orow = reinterpret_cast<float4*>(out + (size_t)row * DD);
#pragma unroll
    for (int j = 0; j < 4; ++j) {
        ushort4 u = ir[j * 64 + lane];
        float4 o;
        o.x = bf2f(u.x) * scale;
        o.y = bf2f(u.y) * scale;
        o.z = bf2f(u.z) * scale;
        o.w = bf2f(u.w) * scale;
        orow[j * 64 + lane] = o;
    }
}

extern "C" void kernel_launch(void* const* d_in, const int* in_sizes, int n_in,
                              void* d_out, int out_size, void* d_ws, size_t ws_size,
                              hipStream_t stream) {
    const float* x = (const float*)d_in[0];
    const float* ema = (const float*)d_in[1];
    // d_in[2] = logit_decay (unused by reference)
    const float* log_tau = (const float*)d_in[3];
    const float* log_blend = (const float*)d_in[4];
    const float* logit_bs = (const float*)d_in[5];
    float* out = (float*)d_out;

    char* ws = (char*)d_ws;
    float* ema_sim = (float*)(ws + (4 << 10));            // 64 KB
    float* norms = (float*)(ws + (68 << 10));             // 64 KB
    float* part = (float*)(ws + (132 << 10));             // 2 MB (8*32*2048 f32)
    unsigned short* onrm = (unsigned short*)(ws + ((size_t)2304 << 10));  // 32 MB

    k_gelu_norm<<<NB * TT / 4, 256, 0, stream>>>(x, ema, onrm, norms, ema_sim);
    k_seqmax<<<NB * NPAIR, 256, 0, stream>>>(onrm, part);
    k_gate<<<NB * TT / 4, 256, 0, stream>>>(onrm, norms, out, ema_sim, part,
                                            log_tau, log_blend, logit_bs);
}